// Round 6
// baseline (416.196 us; speedup 1.0000x reference)
//
#include <hip/hip_runtime.h>

// Lyapunov spectrum via chunked QR scan.
// inp: (T=4096, 9, B=2048) fp32.  out: (3, B) fp32.
// R9: two-pass register replay -- ZERO warm-up HBM traffic (302 MB mandatory
//     + 9.4 MB Q handshake). Pass 1: each chunk converges Q on its OWN first
//     8 steps (J's kept in registers, no accumulation), accumulates steps
//     8..63, publishes Q_end to workspace with device-scope release flag.
//     Pass 2: acquire neighbor's Q_end, replay the 8 register-held steps
//     exactly. Seam contributions become EXACT (Q_end converged e^-19.8).
//     Grid=256 blocks=1/CU (all co-resident; deps point to lower blockIdx
//     -> no spin deadlock). ~300 VGPR -> 1 wave/SIMD, the operating point
//     R7 proved optimal.
// History: only traffic ever moved the score (R5 -75MB -> -4.2us, R7 +75MB
//     -> +6.3us); occupancy/PF/width all null or negative.

typedef float v2 __attribute__((ext_vector_type(2)));
typedef float v4 __attribute__((ext_vector_type(4)));

constexpr int T_STEPS = 4096;
constexpr int BATCH   = 2048;
constexpr int NCHUNK  = 64;
constexpr int KSEG    = T_STEPS / NCHUNK;  // 64
constexpr int WREP    = 8;                 // replayed steps (kept in registers)
constexpr int PF      = 4;                 // prefetch ring depth

constexpr int ROWV2   = 9 * BATCH / 2;     // v2 elements per time step (9216)
constexpr int COLV2   = BATCH / 2;         // v2 elements per m column (1024)

// workspace layout: [0,256) flags (int[64]); [1024, 1024+4718592) Qws
// Qws layout: float2 Qws[9][NCHUNK*COLV2]  (m-major, coalesced per m)
constexpr size_t WS_FLAGS_OFF = 0;
constexpr size_t WS_Q_OFF     = 1024;
constexpr size_t WS_NEEDED    = WS_Q_OFF + (size_t)9 * NCHUNK * COLV2 * 8;

__device__ __forceinline__ v2 rsq2(v2 x) {
    v2 r;
    r.x = __builtin_amdgcn_rsqf(x.x);
    r.y = __builtin_amdgcn_rsqf(x.y);
    return r;
}

__device__ __forceinline__ void lya_step(const v2 J[9], v2 Q[9], v2 d[3]) {
    v2 M[9];
#pragma unroll
    for (int i = 0; i < 3; ++i) {
#pragma unroll
        for (int j = 0; j < 3; ++j) {
            M[i * 3 + j] = J[i * 3 + 0] * Q[0 * 3 + j]
                         + J[i * 3 + 1] * Q[1 * 3 + j]
                         + J[i * 3 + 2] * Q[2 * 3 + j];
        }
    }
    v2 b0x = M[0], b0y = M[3], b0z = M[6];
    v2 d00 = b0x * b0x + b0y * b0y + b0z * b0z;
    v2 r0 = rsq2(d00);
    v2 inv00 = r0 * r0;

    v2 x1x = M[1], x1y = M[4], x1z = M[7];
    v2 c01 = (b0x * x1x + b0y * x1y + b0z * x1z) * inv00;
    v2 b1x = x1x - c01 * b0x;
    v2 b1y = x1y - c01 * b0y;
    v2 b1z = x1z - c01 * b0z;
    v2 d11 = b1x * b1x + b1y * b1y + b1z * b1z;
    v2 r1 = rsq2(d11);
    v2 inv11 = r1 * r1;

    v2 x2x = M[2], x2y = M[5], x2z = M[8];
    v2 c02 = (b0x * x2x + b0y * x2y + b0z * x2z) * inv00;
    v2 c12 = (b1x * x2x + b1y * x2y + b1z * x2z) * inv11;
    v2 b2x = x2x - c02 * b0x - c12 * b1x;
    v2 b2y = x2y - c02 * b0y - c12 * b1y;
    v2 b2z = x2z - c02 * b0z - c12 * b1z;
    v2 d22 = b2x * b2x + b2y * b2y + b2z * b2z;
    v2 r2 = rsq2(d22);

    Q[0] = b0x * r0; Q[3] = b0y * r0; Q[6] = b0z * r0;
    Q[1] = b1x * r1; Q[4] = b1y * r1; Q[7] = b1z * r1;
    Q[2] = b2x * r2; Q[5] = b2y * r2; Q[8] = b2z * r2;
    d[0] = d00; d[1] = d11; d[2] = d22;
}

__global__ __launch_bounds__(256) void lya_replay_kernel(const float* __restrict__ inp,
                                                         float* __restrict__ out,
                                                         void* __restrict__ ws) {
    const int tid   = blockIdx.x * 256 + threadIdx.x;
    const int l     = tid & (COLV2 - 1);   // thread-in-chunk, batches 2l, 2l+1
    const int chunk = tid >> 10;           // 1024 threads/chunk = 4 blocks
    const int seg   = chunk * KSEG;

    int*  flags = (int*)((char*)ws + WS_FLAGS_OFF);
    v2*   Qws   = (v2*)((char*)ws + WS_Q_OFF);
    const int gl = chunk * COLV2 + l;      // global thread slot for Qws

    const v2* __restrict__ base = (const v2*)inp;

    v2 one = {1.f, 1.f}, zero = {0.f, 0.f};
    v2 Q[9] = {one, zero, zero,
               zero, one, zero,
               zero, zero, one};
    v2 acc0 = zero, acc1 = zero, acc2 = zero;

    // Preload PF-deep ring: steps seg .. seg+PF-1 (max 4032+3 < 4096).
    v2 Jb[PF][9];
#pragma unroll
    for (int r = 0; r < PF; ++r) {
        const v2* p = base + (size_t)(seg + r) * ROWV2 + l;
#pragma unroll
        for (int m = 0; m < 9; ++m) Jb[r][m] = p[(size_t)m * COLV2];
    }

    v2 d[3];
    v2 Jrep[WREP][9];   // register-held first-WREP Jacobians for pass-2 replay

    // ---- Pass 1a: steps 0..WREP-1 of OWN segment. Converge Q from identity,
    //      capture J into Jrep, no accumulation. Fully unrolled (static idx).
#pragma unroll
    for (int i = 0; i < WREP; i += PF) {
#pragma unroll
        for (int r = 0; r < PF; ++r) {
#pragma unroll
            for (int m = 0; m < 9; ++m) Jrep[i + r][m] = Jb[r][m];
            lya_step(Jb[r], Q, d);
            const v2* p = base + (size_t)(seg + i + r + PF) * ROWV2 + l;
#pragma unroll
            for (int m = 0; m < 9; ++m) Jb[r][m] = p[(size_t)m * COLV2];
        }
    }

    // ---- Pass 1b: steps WREP..KSEG-1, accumulate (eps <= e^-2.5, as R6/R8).
    for (int i = WREP; i < KSEG; i += PF) {
        v2 p0 = one, p1 = one, p2 = one;
#pragma unroll
        for (int r = 0; r < PF; ++r) {
            lya_step(Jb[r], Q, d);
            p0 *= d[0]; p1 *= d[1]; p2 *= d[2];
            int tp = seg + i + r + PF;
            if (tp > T_STEPS - 1) tp = T_STEPS - 1;   // tail: clamped redundant read
            const v2* p = base + (size_t)tp * ROWV2 + l;
#pragma unroll
            for (int m = 0; m < 9; ++m) Jb[r][m] = p[(size_t)m * COLV2];
        }
        acc0.x += __log2f(p0.x); acc0.y += __log2f(p0.y);
        acc1.x += __log2f(p1.x); acc1.y += __log2f(p1.y);
        acc2.x += __log2f(p2.x); acc2.y += __log2f(p2.y);
    }

    // ---- Publish Q_end(chunk) (converged to ~e^-19.8: effectively exact).
#pragma unroll
    for (int m = 0; m < 9; ++m)
        Qws[(size_t)m * (NCHUNK * COLV2) + gl] = Q[m];
    __syncthreads();                       // all block stores issued (vmcnt 0)
    if (threadIdx.x == 0) {
        __threadfence();                   // device-scope: XCD-L2 writeback
        __hip_atomic_fetch_add(&flags[chunk], 1, __ATOMIC_RELEASE,
                               __HIP_MEMORY_SCOPE_AGENT);
    }

    // ---- Acquire neighbor's Q_end (chunk 0: identity = true start).
    if (chunk > 0) {
        if (threadIdx.x == 0) {
            while (__hip_atomic_load(&flags[chunk - 1], __ATOMIC_ACQUIRE,
                                     __HIP_MEMORY_SCOPE_AGENT) < 4) {
                __builtin_amdgcn_s_sleep(2);
            }
        }
        __syncthreads();
#pragma unroll
        for (int m = 0; m < 9; ++m)
            Q[m] = Qws[(size_t)m * (NCHUNK * COLV2) + (gl - COLV2)];
    } else {
        Q[0] = one;  Q[1] = zero; Q[2] = zero;
        Q[3] = zero; Q[4] = one;  Q[5] = zero;
        Q[6] = zero; Q[7] = zero; Q[8] = one;
    }

    // ---- Pass 2: replay the WREP register-held steps with the true incoming
    //      Q. These contributions are exact (replaces warm-up entirely).
#pragma unroll
    for (int i = 0; i < WREP; i += PF) {
        v2 p0 = one, p1 = one, p2 = one;
#pragma unroll
        for (int r = 0; r < PF; ++r) {
            lya_step(Jrep[i + r], Q, d);
            p0 *= d[0]; p1 *= d[1]; p2 *= d[2];
        }
        acc0.x += __log2f(p0.x); acc0.y += __log2f(p0.y);
        acc1.x += __log2f(p1.x); acc1.y += __log2f(p1.y);
        acc2.x += __log2f(p2.x); acc2.y += __log2f(p2.y);
    }

    // log||b|| = 0.5*ln2*log2(d);  Lya = sum / (T*dt)
    const float scale = 0.5f * 0.69314718056f / (T_STEPS * 0.01f);
    const int b0 = l * 2;
    atomicAdd(&out[0 * BATCH + b0],     acc0.x * scale);
    atomicAdd(&out[0 * BATCH + b0 + 1], acc0.y * scale);
    atomicAdd(&out[1 * BATCH + b0],     acc1.x * scale);
    atomicAdd(&out[1 * BATCH + b0 + 1], acc1.y * scale);
    atomicAdd(&out[2 * BATCH + b0],     acc2.x * scale);
    atomicAdd(&out[2 * BATCH + b0 + 1], acc2.y * scale);
}

// ---------- Fallback (R8, 398.8us): used if workspace is too small ----------

constexpr int ROWV4 = 9 * BATCH / 4;
constexpr int COLV4 = BATCH / 4;
constexpr int WARM  = 8;

__device__ __forceinline__ v4 rsq4(v4 x) {
    v4 r;
    r.x = __builtin_amdgcn_rsqf(x.x);
    r.y = __builtin_amdgcn_rsqf(x.y);
    r.z = __builtin_amdgcn_rsqf(x.z);
    r.w = __builtin_amdgcn_rsqf(x.w);
    return r;
}

__device__ __forceinline__ void lya_step4(const v4 J[9], v4 Q[9], v4 d[3]) {
    v4 M[9];
#pragma unroll
    for (int i = 0; i < 3; ++i)
#pragma unroll
        for (int j = 0; j < 3; ++j)
            M[i * 3 + j] = J[i * 3 + 0] * Q[0 * 3 + j]
                         + J[i * 3 + 1] * Q[1 * 3 + j]
                         + J[i * 3 + 2] * Q[2 * 3 + j];
    v4 b0x = M[0], b0y = M[3], b0z = M[6];
    v4 d00 = b0x * b0x + b0y * b0y + b0z * b0z;
    v4 r0 = rsq4(d00);
    v4 inv00 = r0 * r0;
    v4 x1x = M[1], x1y = M[4], x1z = M[7];
    v4 c01 = (b0x * x1x + b0y * x1y + b0z * x1z) * inv00;
    v4 b1x = x1x - c01 * b0x, b1y = x1y - c01 * b0y, b1z = x1z - c01 * b0z;
    v4 d11 = b1x * b1x + b1y * b1y + b1z * b1z;
    v4 r1 = rsq4(d11);
    v4 inv11 = r1 * r1;
    v4 x2x = M[2], x2y = M[5], x2z = M[8];
    v4 c02 = (b0x * x2x + b0y * x2y + b0z * x2z) * inv00;
    v4 c12 = (b1x * x2x + b1y * x2y + b1z * x2z) * inv11;
    v4 b2x = x2x - c02 * b0x - c12 * b1x;
    v4 b2y = x2y - c02 * b0y - c12 * b1y;
    v4 b2z = x2z - c02 * b0z - c12 * b1z;
    v4 d22 = b2x * b2x + b2y * b2y + b2z * b2z;
    v4 r2 = rsq4(d22);
    Q[0] = b0x * r0; Q[3] = b0y * r0; Q[6] = b0z * r0;
    Q[1] = b1x * r1; Q[4] = b1y * r1; Q[7] = b1z * r1;
    Q[2] = b2x * r2; Q[5] = b2y * r2; Q[8] = b2z * r2;
    d[0] = d00; d[1] = d11; d[2] = d22;
}

__global__ __launch_bounds__(128) void lya_kernel_fb(const float* __restrict__ inp,
                                                     float* __restrict__ out) {
    const int tid   = blockIdx.x * 128 + threadIdx.x;
    const int l     = tid & (COLV4 - 1);
    const int chunk = tid >> 9;
    const int kacc  = chunk * KSEG;
    const int s0    = (kacc >= WARM) ? (kacc - WARM) : 0;
    const int nwarm = kacc - s0;

    const v4* __restrict__ base = (const v4*)inp;
    v4 one = {1.f, 1.f, 1.f, 1.f}, zero = {0.f, 0.f, 0.f, 0.f};
    v4 Q[9] = {one, zero, zero, zero, one, zero, zero, zero, one};
    v4 acc0 = zero, acc1 = zero, acc2 = zero;

    v4 Jb[PF][9];
#pragma unroll
    for (int r = 0; r < PF; ++r) {
        const v4* p = base + (size_t)(s0 + r) * ROWV4 + l;
#pragma unroll
        for (int m = 0; m < 9; ++m) Jb[r][m] = p[(size_t)m * COLV4];
    }
    v4 d[3];
    for (int i = 0; i < nwarm; i += PF) {
#pragma unroll
        for (int r = 0; r < PF; ++r) {
            lya_step4(Jb[r], Q, d);
            const v4* p = base + (size_t)(s0 + i + r + PF) * ROWV4 + l;
#pragma unroll
            for (int m = 0; m < 9; ++m) Jb[r][m] = p[(size_t)m * COLV4];
        }
    }
    for (int i = nwarm; i < nwarm + KSEG; i += PF) {
        v4 p0 = one, p1 = one, p2 = one;
#pragma unroll
        for (int r = 0; r < PF; ++r) {
            lya_step4(Jb[r], Q, d);
            p0 *= d[0]; p1 *= d[1]; p2 *= d[2];
            int tp = s0 + i + r + PF;
            if (tp > T_STEPS - 1) tp = T_STEPS - 1;
            const v4* p = base + (size_t)tp * ROWV4 + l;
#pragma unroll
            for (int m = 0; m < 9; ++m) Jb[r][m] = p[(size_t)m * COLV4];
        }
        acc0.x += __log2f(p0.x); acc0.y += __log2f(p0.y);
        acc0.z += __log2f(p0.z); acc0.w += __log2f(p0.w);
        acc1.x += __log2f(p1.x); acc1.y += __log2f(p1.y);
        acc1.z += __log2f(p1.z); acc1.w += __log2f(p1.w);
        acc2.x += __log2f(p2.x); acc2.y += __log2f(p2.y);
        acc2.z += __log2f(p2.z); acc2.w += __log2f(p2.w);
    }
    const float scale = 0.5f * 0.69314718056f / (T_STEPS * 0.01f);
    const int b0 = l * 4;
#pragma unroll
    for (int c = 0; c < 4; ++c) {
        atomicAdd(&out[0 * BATCH + b0 + c], ((const float*)&acc0)[c] * scale);
        atomicAdd(&out[1 * BATCH + b0 + c], ((const float*)&acc1)[c] * scale);
        atomicAdd(&out[2 * BATCH + b0 + c], ((const float*)&acc2)[c] * scale);
    }
}

extern "C" void kernel_launch(void* const* d_in, const int* in_sizes, int n_in,
                              void* d_out, int out_size, void* d_ws, size_t ws_size,
                              hipStream_t stream) {
    const float* inp = (const float*)d_in[0];
    float* out = (float*)d_out;

    hipMemsetAsync(out, 0, (size_t)out_size * sizeof(float), stream);

    if (d_ws != nullptr && ws_size >= WS_NEEDED) {
        hipMemsetAsync(d_ws, 0, WS_Q_OFF, stream);   // zero the 64 flags
        // 64 chunks x 1024 threads = 256 blocks of 256 = 1 block/CU,
        // all co-resident (required for the flag handshake).
        dim3 grid(NCHUNK * COLV2 / 256);
        dim3 block(256);
        lya_replay_kernel<<<grid, block, 0, stream>>>(inp, out, d_ws);
    } else {
        dim3 grid(NCHUNK * COLV4 / 128);
        dim3 block(128);
        lya_kernel_fb<<<grid, block, 0, stream>>>(inp, out);
    }
}

// Round 7
// 396.787 us; speedup vs baseline: 1.0489x; 1.0489x over previous
//
#include <hip/hip_runtime.h>

// Lyapunov spectrum via chunked QR scan with warm-up re-convergence.
// inp: (T=4096, 9, B=2048) fp32.  out: (3, B) fp32.
// R10: revert to R8 (best verified, 398.8us) + peel the final PF-group of
//      the accumulation loop so it issues NO prefetch: removes 64 chunks x
//      4 steps x 73.7KB = 18.9 MB of never-used cross-segment reads and the
//      per-iteration clamp. Each chunk now reads exactly WARM+KSEG = 72
//      steps -- the structural minimum for this decomposition.
// Experiment ledger: R4 thinner threads +7.7; R5 WARM16 -4.2; R6 WARM8 -2.5
//      (PF=8 null, vmcnt cap); R7 2 waves/SIMD +6.3; R8 v4 width ~0; R9
//      two-pass replay +17.4 (handshake+VGPR cost >> 38MB saved). Only
//      traffic cuts ever won; marginal rate ~0.06us/MB (input straddles L3).

typedef float v4 __attribute__((ext_vector_type(4)));

constexpr int T_STEPS = 4096;
constexpr int BATCH   = 2048;
constexpr int NCHUNK  = 64;
constexpr int KSEG    = T_STEPS / NCHUNK;  // 64
constexpr int WARM    = 8;                 // gap ~0.31/step; err 2nd-order in e^-2.5
constexpr int PF      = 4;                 // ring depth (divides WARM and KSEG)

constexpr int ROWV4   = 9 * BATCH / 4;     // v4 elements per time step (4608)
constexpr int COLV4   = BATCH / 4;         // v4 elements per m column (512)

__device__ __forceinline__ v4 rsq4(v4 x) {
    v4 r;
    r.x = __builtin_amdgcn_rsqf(x.x);
    r.y = __builtin_amdgcn_rsqf(x.y);
    r.z = __builtin_amdgcn_rsqf(x.z);
    r.w = __builtin_amdgcn_rsqf(x.w);
    return r;
}

__device__ __forceinline__ void lya_step(const v4 J[9], v4 Q[9], v4 d[3]) {
    // M = J * Q  (four independent 3x3 systems in the four v4 lanes)
    v4 M[9];
#pragma unroll
    for (int i = 0; i < 3; ++i) {
#pragma unroll
        for (int j = 0; j < 3; ++j) {
            M[i * 3 + j] = J[i * 3 + 0] * Q[0 * 3 + j]
                         + J[i * 3 + 1] * Q[1 * 3 + j]
                         + J[i * 3 + 2] * Q[2 * 3 + j];
        }
    }
    // Classical Gram-Schmidt (projections vs original cols), 1/d = rsq^2
    v4 b0x = M[0], b0y = M[3], b0z = M[6];
    v4 d00 = b0x * b0x + b0y * b0y + b0z * b0z;
    v4 r0 = rsq4(d00);
    v4 inv00 = r0 * r0;

    v4 x1x = M[1], x1y = M[4], x1z = M[7];
    v4 c01 = (b0x * x1x + b0y * x1y + b0z * x1z) * inv00;
    v4 b1x = x1x - c01 * b0x;
    v4 b1y = x1y - c01 * b0y;
    v4 b1z = x1z - c01 * b0z;
    v4 d11 = b1x * b1x + b1y * b1y + b1z * b1z;
    v4 r1 = rsq4(d11);
    v4 inv11 = r1 * r1;

    v4 x2x = M[2], x2y = M[5], x2z = M[8];
    v4 c02 = (b0x * x2x + b0y * x2y + b0z * x2z) * inv00;
    v4 c12 = (b1x * x2x + b1y * x2y + b1z * x2z) * inv11;
    v4 b2x = x2x - c02 * b0x - c12 * b1x;
    v4 b2y = x2y - c02 * b0y - c12 * b1y;
    v4 b2z = x2z - c02 * b0z - c12 * b1z;
    v4 d22 = b2x * b2x + b2y * b2y + b2z * b2z;
    v4 r2 = rsq4(d22);

    Q[0] = b0x * r0; Q[3] = b0y * r0; Q[6] = b0z * r0;
    Q[1] = b1x * r1; Q[4] = b1y * r1; Q[7] = b1z * r1;
    Q[2] = b2x * r2; Q[5] = b2y * r2; Q[8] = b2z * r2;
    d[0] = d00; d[1] = d11; d[2] = d22;
}

__global__ __launch_bounds__(128) void lya_kernel(const float* __restrict__ inp,
                                                  float* __restrict__ out) {
    const int tid   = blockIdx.x * 128 + threadIdx.x;
    const int l     = tid & (COLV4 - 1);   // thread-in-chunk, batches 4l..4l+3
    const int chunk = tid >> 9;            // 512 threads/chunk
    const int kacc  = chunk * KSEG;
    const int s0    = (kacc >= WARM) ? (kacc - WARM) : 0;
    const int nwarm = kacc - s0;           // 0 (chunk 0) or WARM

    const v4* __restrict__ base = (const v4*)inp;

    v4 one = {1.f, 1.f, 1.f, 1.f}, zero = {0.f, 0.f, 0.f, 0.f};
    v4 Q[9] = {one, zero, zero,
               zero, one, zero,
               zero, zero, one};
    v4 acc0 = zero, acc1 = zero, acc2 = zero;

    // Preload PF-deep ring: steps s0 .. s0+PF-1.
    v4 Jb[PF][9];
#pragma unroll
    for (int r = 0; r < PF; ++r) {
        const v4* p = base + (size_t)(s0 + r) * ROWV4 + l;
#pragma unroll
        for (int m = 0; m < 9; ++m) Jb[r][m] = p[(size_t)m * COLV4];
    }

    v4 d[3];

    // Warm-up: re-converge Q, discard log-norms. Prefetch t = s0+i+r+PF
    // (max = kacc+PF-1, strictly inside own segment).
    for (int i = 0; i < nwarm; i += PF) {
#pragma unroll
        for (int r = 0; r < PF; ++r) {
            lya_step(Jb[r], Q, d);
            const v4* p = base + (size_t)(s0 + i + r + PF) * ROWV4 + l;
#pragma unroll
            for (int m = 0; m < 9; ++m) Jb[r][m] = p[(size_t)m * COLV4];
        }
    }

    // Accumulation, all but the last PF-group: prefetch stays in-segment
    // (max tp = kacc+KSEG-1). No clamp needed, no cross-segment reads.
    for (int i = nwarm; i < nwarm + KSEG - PF; i += PF) {
        v4 p0 = one, p1 = one, p2 = one;
#pragma unroll
        for (int r = 0; r < PF; ++r) {
            lya_step(Jb[r], Q, d);
            p0 *= d[0]; p1 *= d[1]; p2 *= d[2];
            const v4* p = base + (size_t)(s0 + i + r + PF) * ROWV4 + l;
#pragma unroll
            for (int m = 0; m < 9; ++m) Jb[r][m] = p[(size_t)m * COLV4];
        }
        acc0.x += __log2f(p0.x); acc0.y += __log2f(p0.y);
        acc0.z += __log2f(p0.z); acc0.w += __log2f(p0.w);
        acc1.x += __log2f(p1.x); acc1.y += __log2f(p1.y);
        acc1.z += __log2f(p1.z); acc1.w += __log2f(p1.w);
        acc2.x += __log2f(p2.x); acc2.y += __log2f(p2.y);
        acc2.z += __log2f(p2.z); acc2.w += __log2f(p2.w);
    }

    // Final PF-group: consume the ring, issue NO prefetch (was 18.9 MB of
    // never-used cross-segment reads across the grid).
    {
        v4 p0 = one, p1 = one, p2 = one;
#pragma unroll
        for (int r = 0; r < PF; ++r) {
            lya_step(Jb[r], Q, d);
            p0 *= d[0]; p1 *= d[1]; p2 *= d[2];
        }
        acc0.x += __log2f(p0.x); acc0.y += __log2f(p0.y);
        acc0.z += __log2f(p0.z); acc0.w += __log2f(p0.w);
        acc1.x += __log2f(p1.x); acc1.y += __log2f(p1.y);
        acc1.z += __log2f(p1.z); acc1.w += __log2f(p1.w);
        acc2.x += __log2f(p2.x); acc2.y += __log2f(p2.y);
        acc2.z += __log2f(p2.z); acc2.w += __log2f(p2.w);
    }

    // log||b|| = 0.5*ln2*log2(d);  Lya = sum / (T*dt)
    const float scale = 0.5f * 0.69314718056f / (T_STEPS * 0.01f);
    const int b0 = l * 4;
    atomicAdd(&out[0 * BATCH + b0],     acc0.x * scale);
    atomicAdd(&out[0 * BATCH + b0 + 1], acc0.y * scale);
    atomicAdd(&out[0 * BATCH + b0 + 2], acc0.z * scale);
    atomicAdd(&out[0 * BATCH + b0 + 3], acc0.w * scale);
    atomicAdd(&out[1 * BATCH + b0],     acc1.x * scale);
    atomicAdd(&out[1 * BATCH + b0 + 1], acc1.y * scale);
    atomicAdd(&out[1 * BATCH + b0 + 2], acc1.z * scale);
    atomicAdd(&out[1 * BATCH + b0 + 3], acc1.w * scale);
    atomicAdd(&out[2 * BATCH + b0],     acc2.x * scale);
    atomicAdd(&out[2 * BATCH + b0 + 1], acc2.y * scale);
    atomicAdd(&out[2 * BATCH + b0 + 2], acc2.z * scale);
    atomicAdd(&out[2 * BATCH + b0 + 3], acc2.w * scale);
}

extern "C" void kernel_launch(void* const* d_in, const int* in_sizes, int n_in,
                              void* d_out, int out_size, void* d_ws, size_t ws_size,
                              hipStream_t stream) {
    const float* inp = (const float*)d_in[0];
    float* out = (float*)d_out;

    hipMemsetAsync(out, 0, (size_t)out_size * sizeof(float), stream);

    // NCHUNK chunks x (BATCH/4) threads = 32768 threads = 256 blocks of 128
    // -> exactly 1 block per CU; every CU issues memory traffic.
    dim3 grid(NCHUNK * COLV4 / 128);
    dim3 block(128);
    lya_kernel<<<grid, block, 0, stream>>>(inp, out);
}